// Round 1
// baseline (3015.213 us; speedup 1.0000x reference)
//
#include <hip/hip_runtime.h>
#include <cfloat>
#include <climits>
#include <cstdint>
#include <cstddef>

// Problem constants (fixed by reference file)
#define H 768
#define NQ 64
#define NPASS 500000
#define TOPK 5
#define TN 64              // passages per tile
#define BK 32              // K-chunk
#define NTILES ((NPASS + TN - 1) / TN)   // 7813
#define MAXBLK 1280        // main-kernel grid (5 blocks/CU * 256 CU)
#define EPSN 1e-12f

// Total order on (score, index): higher score wins; ties -> smaller index
// (matches jax.lax.top_k stable ordering).
__device__ __forceinline__ bool better(float s1, int i1, float s2, int i2) {
  return (s1 > s2) || (s1 == s2 && i1 < i2);
}

// Insert into descending sorted top-5 kept in registers (all static indexing).
__device__ __forceinline__ void insert5(float (&s)[TOPK], int (&ix)[TOPK],
                                        float ns, int ni) {
  if (!better(ns, ni, s[TOPK - 1], ix[TOPK - 1])) return;
  s[TOPK - 1] = ns; ix[TOPK - 1] = ni;
#pragma unroll
  for (int r = TOPK - 1; r > 0; --r) {
    if (better(s[r], ix[r], s[r - 1], ix[r - 1])) {
      float a = s[r]; s[r] = s[r - 1]; s[r - 1] = a;
      int b = ix[r]; ix[r] = ix[r - 1]; ix[r - 1] = b;
    }
  }
}

// Kernel 1: L2-normalize queries, store transposed Qt[h][q] for coalesced
// k-slice loads in the main kernel. 64 blocks x 256 threads.
__global__ __launch_bounds__(256) void qnorm_kernel(const float* __restrict__ q,
                                                    float* __restrict__ qt) {
  const int b = blockIdx.x;       // query
  const int t = threadIdx.x;
  const float v0 = q[b * H + t];
  const float v1 = q[b * H + t + 256];
  const float v2 = q[b * H + t + 512];
  float ss = v0 * v0 + v1 * v1 + v2 * v2;
#pragma unroll
  for (int m = 1; m <= 32; m <<= 1) ss += __shfl_xor(ss, m);
  __shared__ float wsum[4];
  __shared__ float scale_s;
  if ((t & 63) == 0) wsum[t >> 6] = ss;
  __syncthreads();
  if (t == 0) {
    float tot = wsum[0] + wsum[1] + wsum[2] + wsum[3];
    scale_s = 1.0f / fmaxf(sqrtf(tot), EPSN);
  }
  __syncthreads();
  const float sc = scale_s;
  qt[(size_t)t * NQ + b] = v0 * sc;
  qt[(size_t)(t + 256) * NQ + b] = v1 * sc;
  qt[(size_t)(t + 512) * NQ + b] = v2 * sc;
}

// Kernel 2: main. Grid-stride over 64-passage tiles. Per tile: stage
// Qt-slice + E-slice into LDS (k-major, contiguous in m/n for b128 inner
// reads), accumulate 4x4 fp32 register tile per thread, accumulate passage
// norms during staging. Then score = dot * (1/max(||e||,eps)) and update
// per-thread running top-5 per query. Block end: intra-wave shuffle merge
// across the 16 passage-lanes -> per-block top-5 per query -> partials.
__global__ __launch_bounds__(256) void sim_topk_kernel(
    const float* __restrict__ ev, const float* __restrict__ qt,
    float* __restrict__ ps, int* __restrict__ pi) {
  __shared__ float Qs[BK * NQ];   // Qs[k][m], 8 KB
  __shared__ float Es[BK * TN];   // Es[k][n], 8 KB
  __shared__ float Rn[TN];        // 1/max(norm,eps) per passage

  const int t = threadIdx.x;
  const int tx = t & 15;          // passage group (4 passages)
  const int ty = t >> 4;          // query group (4 queries)
  const int lp = t >> 3;          // loader passage 0..31 (and +32)
  const int lf = t & 7;           // loader float4 within 32-float chunk

  float ts_[4][TOPK];
  int   ti_[4][TOPK];
#pragma unroll
  for (int j = 0; j < 4; ++j)
#pragma unroll
    for (int r = 0; r < TOPK; ++r) { ts_[j][r] = -FLT_MAX; ti_[j][r] = INT_MAX; }

  for (int tile = blockIdx.x; tile < NTILES; tile += gridDim.x) {
    float acc[4][4];
#pragma unroll
    for (int j = 0; j < 4; ++j)
#pragma unroll
      for (int i = 0; i < 4; ++i) acc[j][i] = 0.f;
    float nrm0 = 0.f, nrm1 = 0.f;

    const int prow0 = tile * TN;
    const bool v0 = (prow0 + lp) < NPASS;
    const bool v1 = (prow0 + lp + 32) < NPASS;
    const float* e0p = ev + (size_t)(prow0 + lp) * H + (lf << 2);
    const float* e1p = e0p + 32 * H;

    for (int kk = 0; kk < H; kk += BK) {
      __syncthreads();
      // ---- stage Q slice: rows t>>4 and (t>>4)+16, 4 cols at (t&15)*4
      {
        const int r = t >> 4, c = (t & 15) << 2;
        const float4 qa = *(const float4*)(qt + (size_t)(kk + r) * NQ + c);
        const float4 qb = *(const float4*)(qt + (size_t)(kk + r + 16) * NQ + c);
        *(float4*)(Qs + r * NQ + c) = qa;
        *(float4*)(Qs + (r + 16) * NQ + c) = qb;
      }
      // ---- stage E slice (transpose to k-major) + norm accumulation
      {
        float4 e0 = make_float4(0.f, 0.f, 0.f, 0.f);
        float4 e1 = make_float4(0.f, 0.f, 0.f, 0.f);
        if (v0) e0 = *(const float4*)(e0p + kk);
        if (v1) e1 = *(const float4*)(e1p + kk);
        nrm0 = fmaf(e0.x, e0.x, fmaf(e0.y, e0.y, fmaf(e0.z, e0.z, fmaf(e0.w, e0.w, nrm0))));
        nrm1 = fmaf(e1.x, e1.x, fmaf(e1.y, e1.y, fmaf(e1.z, e1.z, fmaf(e1.w, e1.w, nrm1))));
        const int kb = lf << 2;
        Es[(kb + 0) * TN + lp] = e0.x;
        Es[(kb + 1) * TN + lp] = e0.y;
        Es[(kb + 2) * TN + lp] = e0.z;
        Es[(kb + 3) * TN + lp] = e0.w;
        Es[(kb + 0) * TN + lp + 32] = e1.x;
        Es[(kb + 1) * TN + lp + 32] = e1.y;
        Es[(kb + 2) * TN + lp + 32] = e1.z;
        Es[(kb + 3) * TN + lp + 32] = e1.w;
      }
      __syncthreads();
      // ---- inner product: 32 k-steps x 16 FMA
#pragma unroll
      for (int k = 0; k < BK; ++k) {
        const float4 rq = *(const float4*)(Qs + k * NQ + (ty << 2));
        const float4 re = *(const float4*)(Es + k * TN + (tx << 2));
        acc[0][0] = fmaf(rq.x, re.x, acc[0][0]);
        acc[0][1] = fmaf(rq.x, re.y, acc[0][1]);
        acc[0][2] = fmaf(rq.x, re.z, acc[0][2]);
        acc[0][3] = fmaf(rq.x, re.w, acc[0][3]);
        acc[1][0] = fmaf(rq.y, re.x, acc[1][0]);
        acc[1][1] = fmaf(rq.y, re.y, acc[1][1]);
        acc[1][2] = fmaf(rq.y, re.z, acc[1][2]);
        acc[1][3] = fmaf(rq.y, re.w, acc[1][3]);
        acc[2][0] = fmaf(rq.z, re.x, acc[2][0]);
        acc[2][1] = fmaf(rq.z, re.y, acc[2][1]);
        acc[2][2] = fmaf(rq.z, re.z, acc[2][2]);
        acc[2][3] = fmaf(rq.z, re.w, acc[2][3]);
        acc[3][0] = fmaf(rq.w, re.x, acc[3][0]);
        acc[3][1] = fmaf(rq.w, re.y, acc[3][1]);
        acc[3][2] = fmaf(rq.w, re.z, acc[3][2]);
        acc[3][3] = fmaf(rq.w, re.w, acc[3][3]);
      }
    }
    // ---- passage norms: 8 loader-lanes per passage -> shuffle reduce
#pragma unroll
    for (int m = 1; m <= 4; m <<= 1) {
      nrm0 += __shfl_xor(nrm0, m);
      nrm1 += __shfl_xor(nrm1, m);
    }
    if (lf == 0) {
      Rn[lp] = 1.0f / fmaxf(sqrtf(nrm0), EPSN);
      Rn[lp + 32] = 1.0f / fmaxf(sqrtf(nrm1), EPSN);
    }
    __syncthreads();
    // ---- score + running top-5 per query
    const int pb = prow0 + (tx << 2);
#pragma unroll
    for (int i = 0; i < 4; ++i) {
      const int idx = pb + i;
      if (idx < NPASS) {
        const float rn = Rn[(tx << 2) + i];
#pragma unroll
        for (int j = 0; j < 4; ++j)
          insert5(ts_[j], ti_[j], acc[j][i] * rn, idx);
      }
    }
  }

  // ---- block-end merge: the 16 tx-lanes of a wave share the same 4 queries.
  // 5 rounds of 16-lane shuffle argmax + pop. Indices are globally unique
  // (each passage scored by exactly one thread), so exactly one lane pops.
#pragma unroll
  for (int j = 0; j < 4; ++j) {
#pragma unroll
    for (int r = 0; r < TOPK; ++r) {
      float cs = ts_[j][0];
      int ci = ti_[j][0];
#pragma unroll
      for (int m = 1; m <= 8; m <<= 1) {
        const float os = __shfl_xor(cs, m);
        const int oi = __shfl_xor(ci, m);
        if (better(os, oi, cs, ci)) { cs = os; ci = oi; }
      }
      if (ti_[j][0] == ci) {
#pragma unroll
        for (int r2 = 0; r2 < TOPK - 1; ++r2) {
          ts_[j][r2] = ts_[j][r2 + 1];
          ti_[j][r2] = ti_[j][r2 + 1];
        }
        ts_[j][TOPK - 1] = -FLT_MAX;
        ti_[j][TOPK - 1] = INT_MAX;
      }
      if (tx == 0) {
        const int q = (ty << 2) + j;
        const size_t o = ((size_t)blockIdx.x * NQ + q) * TOPK + r;
        ps[o] = cs;
        pi[o] = ci;
      }
    }
  }
}

// Kernel 3: final reduce. One block per query; scan nblk*5 partial
// candidates, thread-local top-5, then 5 rounds of LDS argmax extraction.
__global__ __launch_bounds__(256) void final_topk_kernel(
    const float* __restrict__ ps, const int* __restrict__ pi,
    float* __restrict__ out, int nblk) {
  const int q = blockIdx.x;
  const int t = threadIdx.x;
  float ls[TOPK];
  int li[TOPK];
#pragma unroll
  for (int r = 0; r < TOPK; ++r) { ls[r] = -FLT_MAX; li[r] = INT_MAX; }

  const int nc = nblk * TOPK;
  for (int c = t; c < nc; c += 256) {
    const int blk = c / TOPK, slot = c % TOPK;
    const size_t o = ((size_t)blk * NQ + q) * TOPK + slot;
    insert5(ls, li, ps[o], pi[o]);
  }

  __shared__ float ss[256];
  __shared__ int si[256];
  for (int r = 0; r < TOPK; ++r) {
    ss[t] = ls[0];
    si[t] = li[0];
    __syncthreads();
    for (int off = 128; off > 0; off >>= 1) {
      if (t < off) {
        if (better(ss[t + off], si[t + off], ss[t], si[t])) {
          ss[t] = ss[t + off];
          si[t] = si[t + off];
        }
      }
      __syncthreads();
    }
    const float wsc = ss[0];
    const int wix = si[0];
    if (li[0] == wix) {
#pragma unroll
      for (int r2 = 0; r2 < TOPK - 1; ++r2) { ls[r2] = ls[r2 + 1]; li[r2] = li[r2 + 1]; }
      ls[TOPK - 1] = -FLT_MAX;
      li[TOPK - 1] = INT_MAX;
    }
    if (t == 0) {
      out[q * TOPK + r] = (float)wix;               // indices output (as f32)
      out[NQ * TOPK + q * TOPK + r] = wsc;          // scores output
    }
    __syncthreads();
  }
}

extern "C" void kernel_launch(void* const* d_in, const int* in_sizes, int n_in,
                              void* d_out, int out_size, void* d_ws,
                              size_t ws_size, hipStream_t stream) {
  const float* q = (const float*)d_in[0];
  const float* ev = (const float*)d_in[1];
  float* out = (float*)d_out;

  const size_t qt_bytes = (size_t)H * NQ * sizeof(float);  // 196608
  int nblk = MAXBLK;
  // Adapt to workspace size if it's tight (grid-stride handles any nblk).
  const size_t per_blk = (size_t)NQ * TOPK * (sizeof(float) + sizeof(int));
  if (ws_size < qt_bytes + (size_t)nblk * per_blk) {
    size_t avail = ws_size > qt_bytes ? (ws_size - qt_bytes) : per_blk;
    nblk = (int)(avail / per_blk);
    if (nblk < 1) nblk = 1;
    if (nblk > MAXBLK) nblk = MAXBLK;
  }

  float* qt = (float*)d_ws;
  float* ps = (float*)((char*)d_ws + qt_bytes);
  int* pi = (int*)((char*)d_ws + qt_bytes + (size_t)nblk * NQ * TOPK * sizeof(float));

  hipLaunchKernelGGL(qnorm_kernel, dim3(NQ), dim3(256), 0, stream, q, qt);
  hipLaunchKernelGGL(sim_topk_kernel, dim3(nblk), dim3(256), 0, stream, ev, qt,
                     ps, pi);
  hipLaunchKernelGGL(final_topk_kernel, dim3(NQ), dim3(256), 0, stream, ps, pi,
                     out, nblk);
}